// Round 1
// 428.672 us; speedup vs baseline: 1.0614x; 1.0614x over previous
//
#include <hip/hip_runtime.h>

// Problem: B=64, N=257, D=1024, H=16, HD=64
#define B_   64
#define N_   257
#define D_   1024
#define H_   16
#define HD_  64
#define M_   (B_*N_)      // 16448 rows (b*257+n)
#define CK_  96           // attention key-chunk (3 chunks cover 288 >= 257)
#define VTS_ 128          // Vt row stride
#define PLS_ 104          // Pl row stride (8*odd)

typedef __bf16 bf16x8 __attribute__((ext_vector_type(8)));
typedef __bf16 bf16x4 __attribute__((ext_vector_type(4)));
typedef float  f32x4  __attribute__((ext_vector_type(4)));

// async global->LDS, 16B per lane; LDS dest = wave-uniform base + lane*16
__device__ __forceinline__ void gload_lds16(const void* g, void* l) {
    __builtin_amdgcn_global_load_lds(
        (const __attribute__((address_space(1))) void*)g,
        (__attribute__((address_space(3))) void*)l, 16, 0, 0);
}

#define MEMF() asm volatile("" ::: "memory")
#define BARRIER() do { MEMF(); __builtin_amdgcn_s_barrier(); MEMF(); } while (0)
#define WAITV(n) asm volatile("s_waitcnt vmcnt(" #n ")" ::: "memory")

// ---------------- merged f32 -> bf16 convert (x, w1, w2 in one launch) ----------------
#define XQ_  4210688           // x quads
#define W1Q_ 786432            // w1 quads
#define W2Q_ 262144            // w2 quads
__global__ __launch_bounds__(256) void cvt_all(const float* __restrict__ x,
                                               const float* __restrict__ w1,
                                               const float* __restrict__ w2,
                                               __bf16* __restrict__ xb,
                                               __bf16* __restrict__ w1b,
                                               __bf16* __restrict__ w2b) {
    int i = blockIdx.x * 256 + threadIdx.x;
    const float* src; __bf16* dst; int j;
    if (i < XQ_) { src = x; dst = xb; j = i; }
    else if (i < XQ_ + W1Q_) { src = w1; dst = w1b; j = i - XQ_; }
    else if (i < XQ_ + W1Q_ + W2Q_) { src = w2; dst = w2b; j = i - XQ_ - W1Q_; }
    else return;
    float4 v = reinterpret_cast<const float4*>(src)[j];
    bf16x4 o;
    o[0] = (__bf16)v.x; o[1] = (__bf16)v.y; o[2] = (__bf16)v.z; o[3] = (__bf16)v.w;
    *reinterpret_cast<bf16x4*>(dst + (size_t)j * 4) = o;
}

// ---------------- 256x256 8-wave pipelined GEMM (bt), 4 phases/K-tile ----------------
// Schedule ledger (per K-tile t, buffers b=t&1, chunks = 2 gloads/thread each):
//   q0: ds_read A-front+B-front(t); issue A-front(t+1); vmcnt(4) [=> B-back(t) landed]
//   q1: ds_read B-back(t);          issue B-front(t+1); vmcnt(4) [=> A-back(t) landed]
//   q2: ds_read A-back(t);          issue B-back(t+1);  (no wait)
//   q3: (regs only);                issue A-back(t+1);  vmcnt(4) [=> A/B-front(t+1) landed]
// Chunks defined by consumption: A-front = rows {0-63,128-191} (wm=0/1 rq0 frags),
// B-front = rows {p*64+0..31} (c01 frags of all wn). Max 8 loads in flight; never
// drained to 0 in-loop. t=15 re-stages tile 15 into the dead buffer (uniform ledger),
// drained once before LDS epilogue reuse.
template<int NT, int MODE>   // NT = col tiles (12 qkv -> q/k/v scatter, 4 out -> f32)
__global__ __launch_bounds__(512, 2) void gemm256(const __bf16* __restrict__ A,
                                                  const __bf16* __restrict__ W,
                                                  const float* __restrict__ bias,
                                                  __bf16* __restrict__ qo,
                                                  __bf16* __restrict__ ko,
                                                  __bf16* __restrict__ vo,
                                                  float* __restrict__ fo) {
    __shared__ __align__(16) char smem[131072];
    constexpr int NWG = 65 * NT;
    constexpr int qd = NWG >> 3, rm = NWG & 7;
    const int orig = blockIdx.x;
    const int xcd = orig & 7, loc = orig >> 3;
    const int wgid = (xcd < rm ? xcd * (qd + 1) : rm * (qd + 1) + (xcd - rm) * qd) + loc;
    const int rowt = wgid / NT, colt = wgid - rowt * NT;
    const int row0 = rowt * 256, col0 = colt * 256;

    const int tid = threadIdx.x, lane = tid & 63, wv = tid >> 6;
    const int wm = wv >> 2, wn = wv & 3;
    const int fr = lane & 15, fq = lane >> 4, frs = lane & 7;

    // staging: per-thread source offsets (elements), source-swizzled (g ^= row&7)
    const int pr = tid >> 3;                       // 0..63 within a 64-row piece
    const int pg = ((tid & 7) ^ (pr & 7)) * 8;
    int srcA[4];                                   // pieces rows {0,128 | 64,192}
    {
        const int prow[4] = {0, 128, 64, 192};
#pragma unroll
        for (int p = 0; p < 4; ++p) {
            int rg = row0 + prow[p] + pr;
            if (rg > M_ - 1) rg = M_ - 1;          // M-tail clamp (rows unused in C)
            srcA[p] = rg * 1024 + pg;
        }
    }
    int srcW[2], ldsW[2];                          // B-front sub-pieces e=0,1; back = +32 rows
#pragma unroll
    for (int e = 0; e < 2; ++e) {
        const int wb = (wv >> 1) * 64 + e * 16 + (wv & 1) * 8;
        srcW[e] = (col0 + wb + (lane >> 3)) * 1024 + pg;
        ldsW[e] = wb * 128;
    }
    char* const At0 = smem;
    char* const At1 = smem + 32768;
    char* const Wt0 = smem + 65536;
    char* const Wt1 = smem + 98304;

#define STG_AF(dst, kk) do { gload_lds16(A + srcA[0] + (kk), (dst) + wv * 1024); \
                             gload_lds16(A + srcA[1] + (kk), (dst) + 16384 + wv * 1024); } while (0)
#define STG_AB(dst, kk) do { gload_lds16(A + srcA[2] + (kk), (dst) + 8192 + wv * 1024); \
                             gload_lds16(A + srcA[3] + (kk), (dst) + 24576 + wv * 1024); } while (0)
#define STG_WF(dst, kk) do { gload_lds16(W + srcW[0] + (kk), (dst) + ldsW[0]); \
                             gload_lds16(W + srcW[1] + (kk), (dst) + ldsW[1]); } while (0)
#define STG_WB(dst, kk) do { gload_lds16(W + srcW[0] + 32768 + (kk), (dst) + ldsW[0] + 4096); \
                             gload_lds16(W + srcW[1] + 32768 + (kk), (dst) + ldsW[1] + 4096); } while (0)
#define LD_A(buf, rqo) do { \
    _Pragma("unroll") for (int i = 0; i < 4; ++i) \
    _Pragma("unroll") for (int ks = 0; ks < 2; ++ks) \
        af[i][ks] = *(const bf16x8*)((buf) + (wm * 128 + (rqo) + i * 16 + fr) * 128 \
                                           + (((ks * 4 + fq) ^ frs) << 4)); \
} while (0)
#define LD_B(buf, co, bw) do { \
    _Pragma("unroll") for (int j = 0; j < 2; ++j) \
    _Pragma("unroll") for (int ks = 0; ks < 2; ++ks) \
        bw[j][ks] = *(const bf16x8*)((buf) + (wn * 64 + (co) + j * 16 + fr) * 128 \
                                           + (((ks * 4 + fq) ^ frs) << 4)); \
} while (0)
#define MFMA_Q(i0, j0, bw) do { \
    __builtin_amdgcn_s_setprio(1); \
    _Pragma("unroll") for (int i = 0; i < 4; ++i) \
    _Pragma("unroll") for (int j = 0; j < 2; ++j) \
    _Pragma("unroll") for (int ks = 0; ks < 2; ++ks) \
        acc[(i0) + i][(j0) + j] = __builtin_amdgcn_mfma_f32_16x16x32_bf16( \
            af[i][ks], bw[j][ks], acc[(i0) + i][(j0) + j], 0, 0, 0); \
    __builtin_amdgcn_s_setprio(0); \
} while (0)

    f32x4 acc[8][4] = {};
    bf16x8 af[4][2], bw0[2][2], bw1[2][2];

    // prologue: stage tile 0, wait for A/B-front (4 loads may stay in flight)
    STG_AF(At0, 0); STG_WF(Wt0, 0); STG_WB(Wt0, 0); STG_AB(At0, 0);
    WAITV(4);
    BARRIER();

#pragma unroll 2
    for (int t = 0; t < 16; ++t) {
        char* const Ac = (t & 1) ? At1 : At0;
        char* const Wc = (t & 1) ? Wt1 : Wt0;
        char* const An = (t & 1) ? At0 : At1;
        char* const Wn = (t & 1) ? Wt0 : Wt1;
        const int kk = (t < 15) ? (t + 1) * 64 : 960;   // t=15: dummy re-stage (dead buf)
        // q0: rows rq0, cols c01
        LD_A(Ac, 0);
        LD_B(Wc, 0, bw0);
        STG_AF(An, kk);
        WAITV(4);
        BARRIER();
        MFMA_Q(0, 0, bw0);
        BARRIER();
        // q1: rq0, c23
        LD_B(Wc, 32, bw1);
        STG_WF(Wn, kk);
        WAITV(4);
        BARRIER();
        MFMA_Q(0, 2, bw1);
        BARRIER();
        // q2: rq1, c23
        LD_A(Ac, 64);
        STG_WB(Wn, kk);
        BARRIER();
        MFMA_Q(4, 2, bw1);
        BARRIER();
        // q3: rq1, c01 (all regs)
        STG_AB(An, kk);
        WAITV(4);
        BARRIER();
        MFMA_Q(4, 0, bw0);
        BARRIER();
    }
    WAITV(0);      // drain dummy stages before smem reuse / exit
    BARRIER();

    if constexpr (MODE == 0) {
        // epilogue: acc -> LDS (bias+scale, XOR-swizzled cols) -> coalesced q/k/v scatter
        const int which = colt >> 2;
        __bf16* const dst = which == 0 ? qo : (which == 1 ? ko : vo);
        const float scale = which == 0 ? 0.125f : 1.0f;
        float bj[4];
#pragma unroll
        for (int j = 0; j < 4; ++j) bj[j] = bias[col0 + wn * 64 + j * 16 + fr];
        __bf16* const Ct = (__bf16*)smem;
#pragma unroll
        for (int i = 0; i < 8; ++i) {
            const int rb = wm * 128 + (i >> 2) * 64 + (i & 3) * 16 + fq * 4;
#pragma unroll
            for (int r = 0; r < 4; ++r) {
                const int row = rb + r;
#pragma unroll
                for (int j = 0; j < 4; ++j) {
                    const int cu = wn * 64 + j * 16 + fr;
                    Ct[row * 256 + (((cu >> 3) ^ (row & 7)) * 8) + (cu & 7)] =
                        (__bf16)((acc[i][j][r] + bj[j]) * scale);
                }
            }
        }
        BARRIER();
#pragma unroll
        for (int p = 0; p < 16; ++p) {
            const int row = p * 16 + (tid >> 5);
            const int m = row0 + row;
            if (m < M_) {
                const int gl = tid & 31;
                bf16x8 v = *(const bf16x8*)(Ct + row * 256 + ((gl ^ (row & 7)) * 8));
                const int cG = col0 + gl * 8;
                const int h = (cG >> 6) & 15, hd = cG & 63;
                const int bb = m / 257, nn = m - bb * 257;
                *reinterpret_cast<bf16x8*>(dst + ((size_t)(bb * 16 + h) * 257 + nn) * 64 + hd) = v;
            }
        }
    } else {
        // epilogue: direct f32 stores + bias
        float bj[4];
#pragma unroll
        for (int j = 0; j < 4; ++j) bj[j] = bias[col0 + wn * 64 + j * 16 + fr];
#pragma unroll
        for (int i = 0; i < 8; ++i) {
            const int rb = wm * 128 + (i >> 2) * 64 + (i & 3) * 16 + fq * 4;
#pragma unroll
            for (int r = 0; r < 4; ++r) {
                const int m = row0 + rb + r;
                if (m < M_) {
                    float* const p = fo + (size_t)m * 1024 + col0 + wn * 64 + fr;
#pragma unroll
                    for (int j = 0; j < 4; ++j) p[j * 16] = acc[i][j][r] + bj[j];
                }
            }
        }
    }
#undef STG_AF
#undef STG_AB
#undef STG_WF
#undef STG_WB
#undef LD_A
#undef LD_B
#undef MFMA_Q
}

// ---------------- fused masked attention (rows 0..255; 3 key chunks of 96) ----------------
__global__ __launch_bounds__(256) void attn_kernel(const __bf16* __restrict__ qw,
                                                   const __bf16* __restrict__ kw,
                                                   const __bf16* __restrict__ vw,
                                                   const int* __restrict__ mask,
                                                   __bf16* __restrict__ attn) {
    const int bh = blockIdx.x;
    const int bb = bh >> 4, hh = bh & 15;
    const int q0 = blockIdx.y * 64;      // 0..192, all 64 rows valid
    const int tid = threadIdx.x, lane = tid & 63, wv = tid >> 6;
    const int fr = lane & 15, fq = lane >> 4;
    const float NEG_INF = -__builtin_inff();

    __shared__ __align__(16) __bf16 Qs[64 * 64];        // [q][hd] swizzled (g ^= row&7)
    __shared__ __align__(16) __bf16 Ks[CK_ * 64];       // [key][hd] swizzled
    __shared__ __align__(16) __bf16 Vt[64 * VTS_];      // [hd][keygrp swizzled]
    __shared__ __align__(16) __bf16 Pl[4][16 * PLS_];   // per-wave P
    __shared__ float maskb[288];

    const __bf16* qg = qw + ((size_t)bh * 257 + q0) * 64;
    const __bf16* kg = kw + (size_t)bh * 257 * 64;
    const __bf16* vg = vw + (size_t)bh * 257 * 64;
    const int* mg = mask + bb * 257;

    for (int idx = tid; idx < 288; idx += 256)
        maskb[idx] = (idx < 257 && mg[idx] == 0) ? 0.0f : NEG_INF;

    // stage Q tile [64][64] async, source-swizzled (all rows valid)
#pragma unroll
    for (int i = 0; i < 2; ++i) {
        const int c = tid + i * 256;
        const int r = c >> 3, g = (c & 7) ^ (r & 7);
        gload_lds16(qg + (size_t)r * 64 + g * 8, (char*)Qs + i * 4096 + wv * 1024);
    }

    float m_run[4] = {NEG_INF, NEG_INF, NEG_INF, NEG_INF};
    float l_run[4] = {};
    f32x4 Oa[4] = {};

    for (int c3 = 0; c3 < 3; ++c3) {
        const int k0 = c3 * CK_;
        __syncthreads();
#pragma unroll
        for (int i = 0; i < 3; ++i) {
            const int c = tid + i * 256;
            const int r = c >> 3, g = (c & 7) ^ (r & 7);
            if (k0 + r < 257)
                gload_lds16(kg + (size_t)(k0 + r) * 64 + g * 8, (char*)Ks + i * 4096 + wv * 1024);
        }
#pragma unroll
        for (int it = 0; it < 3; ++it) {
            const int t = tid + it * 256;
            const int key = t >> 3, grp = t & 7;
            if (k0 + key < 257) {
                bf16x8 v8 = *reinterpret_cast<const bf16x8*>(vg + (size_t)(k0 + key) * 64 + grp * 8);
#pragma unroll
                for (int u = 0; u < 8; ++u) {
                    const int hd = grp * 8 + u;
                    Vt[hd * VTS_ + (((key >> 3) ^ (hd & 7)) * 8) + (key & 7)] = v8[u];
                }
            }
        }
        __syncthreads();

        // S = Q K^T (+ mask bias); q pre-scaled by 1/8
        f32x4 s[6];
        {
            bf16x8 aq[2];
#pragma unroll
            for (int ks = 0; ks < 2; ++ks)
                aq[ks] = *reinterpret_cast<const bf16x8*>(
                    &Qs[(wv * 16 + fr) * 64 + (((ks * 4 + fq) ^ (fr & 7)) * 8)]);
#pragma unroll
            for (int nt = 0; nt < 6; ++nt) {
                f32x4 sa = {};
#pragma unroll
                for (int ks = 0; ks < 2; ++ks) {
                    bf16x8 bk = *reinterpret_cast<const bf16x8*>(
                        &Ks[(nt * 16 + fr) * 64 + (((ks * 4 + fq) ^ (fr & 7)) * 8)]);
                    sa = __builtin_amdgcn_mfma_f32_16x16x32_bf16(aq[ks], bk, sa, 0, 0, 0);
                }
                const float mb = maskb[k0 + nt * 16 + fr];
#pragma unroll
                for (int r = 0; r < 4; ++r) sa[r] += mb;
                s[nt] = sa;
            }
        }
        float alpha[4];
#pragma unroll
        for (int r = 0; r < 4; ++r) {
            float v = s[0][r];
#pragma unroll
            for (int nt = 1; nt < 6; ++nt) v = fmaxf(v, s[nt][r]);
            v = fmaxf(v, __shfl_xor(v, 1));
            v = fmaxf(v, __shfl_xor(v, 2));
            v = fmaxf(v, __shfl_xor(v, 4));
            v = fmaxf(v, __shfl_xor(v, 8));
            const float mnew = fmaxf(m_run[r], v);
            alpha[r] = __expf(m_run[r] - mnew);
            m_run[r] = mnew;
        }
        float sm[4] = {};
#pragma unroll
        for (int nt = 0; nt < 6; ++nt)
#pragma unroll
            for (int r = 0; r < 4; ++r) {
                const float p = __expf(s[nt][r] - m_run[r]);
                s[nt][r] = p;
                sm[r] += p;
            }
#pragma unroll
        for (int r = 0; r < 4; ++r) {
            float v = sm[r];
            v += __shfl_xor(v, 1);
            v += __shfl_xor(v, 2);
            v += __shfl_xor(v, 4);
            v += __shfl_xor(v, 8);
            l_run[r] = l_run[r] * alpha[r] + v;
        }
#pragma unroll
        for (int ot = 0; ot < 4; ++ot)
#pragma unroll
            for (int r = 0; r < 4; ++r) Oa[ot][r] *= alpha[r];
#pragma unroll
        for (int nt = 0; nt < 6; ++nt)
#pragma unroll
            for (int r = 0; r < 4; ++r)
                Pl[wv][(fq * 4 + r) * PLS_ + nt * 16 + fr] = (__bf16)s[nt][r];
        __syncthreads();
        bf16x8 ap[3];
#pragma unroll
        for (int kk = 0; kk < 3; ++kk)
            ap[kk] = *reinterpret_cast<const bf16x8*>(&Pl[wv][fr * PLS_ + kk * 32 + fq * 8]);
#pragma unroll
        for (int ot = 0; ot < 4; ++ot) {
            const int row = ot * 16 + fr;
#pragma unroll
            for (int kk = 0; kk < 3; ++kk) {
                bf16x8 bv = *reinterpret_cast<const bf16x8*>(
                    &Vt[row * VTS_ + (((kk * 4 + fq) ^ (fr & 7)) * 8)]);
                Oa[ot] = __builtin_amdgcn_mfma_f32_16x16x32_bf16(ap[kk], bv, Oa[ot], 0, 0, 0);
            }
        }
    }
    // epilogue (all rows valid)
#pragma unroll
    for (int r = 0; r < 4; ++r) {
        const int n = q0 + wv * 16 + fq * 4 + r;
        const float inv = 1.0f / l_run[r];
#pragma unroll
        for (int ot = 0; ot < 4; ++ot)
            attn[((size_t)(bb * 257 + n)) * 1024 + hh * 64 + ot * 16 + fr] =
                (__bf16)(Oa[ot][r] * inv);
    }
}

// ---------------- attention tail: query row 256, one block per (b,h) ----------------
__global__ __launch_bounds__(320) void attn_tail(const __bf16* __restrict__ qw,
                                                 const __bf16* __restrict__ kw,
                                                 const __bf16* __restrict__ vw,
                                                 const int* __restrict__ mask,
                                                 __bf16* __restrict__ attn) {
    const int bh = blockIdx.x;
    const int bb = bh >> 4, hh = bh & 15;
    const int tid = threadIdx.x, wv = tid >> 6;
    const float NEG_INF = -__builtin_inff();
    __shared__ float pbuf[257];
    __shared__ float red[5];
    __shared__ float gstat[2];   // [0]=max, [1]=sum

    const __bf16* qg = qw + ((size_t)bh * 257 + 256) * 64;
    const __bf16* kg = kw + (size_t)bh * 257 * 64;
    const __bf16* vg = vw + (size_t)bh * 257 * 64;

    float s = NEG_INF;
    if (tid < 257) {
        const __bf16* kr = kg + (size_t)tid * 64;
        float acc = 0.0f;
#pragma unroll
        for (int g = 0; g < 8; ++g) {
            bf16x8 qv = *reinterpret_cast<const bf16x8*>(qg + g * 8);
            bf16x8 kv = *reinterpret_cast<const bf16x8*>(kr + g * 8);
#pragma unroll
            for (int u = 0; u < 8; ++u) acc += (float)qv[u] * (float)kv[u];
        }
        s = (mask[bb * 257 + tid] == 0) ? acc : NEG_INF;   // q pre-scaled by 1/8
    }
    // block max
    float v = s;
#pragma unroll
    for (int d = 1; d < 64; d <<= 1) v = fmaxf(v, __shfl_xor(v, d));
    if ((tid & 63) == 0) red[wv] = v;
    __syncthreads();
    if (tid == 0) {
        float m = red[0];
#pragma unroll
        for (int w = 1; w < 5; ++w) m = fmaxf(m, red[w]);
        gstat[0] = m;
    }
    __syncthreads();
    const float gmax = gstat[0];
    float p = (tid < 257) ? __expf(s - gmax) : 0.0f;
    if (tid < 257) pbuf[tid] = p;
    float sv = p;
#pragma unroll
    for (int d = 1; d < 64; d <<= 1) sv += __shfl_xor(sv, d);
    if ((tid & 63) == 0) red[wv] = sv;
    __syncthreads();
    if (tid == 0) gstat[1] = red[0] + red[1] + red[2] + red[3] + red[4];
    __syncthreads();
    if (tid < 64) {
        const float inv = 1.0f / gstat[1];
        float o = 0.0f;
        for (int j = 0; j < 257; ++j)
            o += pbuf[j] * (float)vg[(size_t)j * 64 + tid];
        attn[((size_t)(bb * 257 + 256)) * 1024 + hh * 64 + tid] = (__bf16)(o * inv);
    }
}

// ---------------- launch ----------------
// ws layout (bytes):
//   x_bf   @ 0          : 16512*1024*2    = 33,816,576
//   w1_bf  @ 33816576   : 3072*1024*2     =  6,291,456
//   w2_bf  @ 40108032   : 1024*1024*2     =  2,097,152
//   q_ws   @ 42205184   : 64*16*257*64*2  = 33,685,504   [b][h][n][hd], pre-scaled 1/8
//   k_ws   @ 75890688   : 33,685,504                      [b][h][n][hd]
//   v_ws   @ 109576192  : 33,685,504                      [b][h][n][hd]
//   a_bf   @ 143261696  : 33,816,576                      attention output, bf16
extern "C" void kernel_launch(void* const* d_in, const int* in_sizes, int n_in,
                              void* d_out, int out_size, void* d_ws, size_t ws_size,
                              hipStream_t stream) {
    const float* x  = (const float*)d_in[0];
    const int* mask = (const int*)d_in[1];
    const float* w1 = (const float*)d_in[2];
    const float* b1 = (const float*)d_in[3];
    const float* w2 = (const float*)d_in[4];
    const float* b2 = (const float*)d_in[5];
    float* out = (float*)d_out;
    char* ws = (char*)d_ws;
    __bf16* x_bf  = (__bf16*)(ws);
    __bf16* w1_bf = (__bf16*)(ws + 33816576);
    __bf16* w2_bf = (__bf16*)(ws + 40108032);
    __bf16* q_ws  = (__bf16*)(ws + 42205184);
    __bf16* k_ws  = (__bf16*)(ws + 75890688);
    __bf16* v_ws  = (__bf16*)(ws + 109576192);
    __bf16* a_bf  = (__bf16*)(ws + 143261696);

    cvt_all<<<20544, 256, 0, stream>>>(x, w1, w2, x_bf, w1_bf, w2_bf);
    gemm256<12, 0><<<780, 512, 0, stream>>>(x_bf, w1_bf, b1, q_ws, k_ws, v_ws, nullptr);
    attn_kernel<<<dim3(1024, 4), 256, 0, stream>>>(q_ws, k_ws, v_ws, mask, a_bf);
    attn_tail<<<1024, 320, 0, stream>>>(q_ws, k_ws, v_ws, mask, a_bf);
    gemm256<4, 1><<<260, 512, 0, stream>>>(a_bf, w2_bf, b2, nullptr, nullptr, nullptr, out);
}

// Round 2
// 416.796 us; speedup vs baseline: 1.0916x; 1.0285x over previous
//
#include <hip/hip_runtime.h>

// Problem: B=64, N=257, D=1024, H=16, HD=64
#define B_   64
#define N_   257
#define D_   1024
#define H_   16
#define HD_  64
#define M_   (B_*N_)      // 16448 rows (b*257+n)
#define CK_  96           // attention key-chunk (3 chunks cover 288 >= 257)
#define VTS_ 128          // Vt row stride
#define PLS_ 104          // Pl row stride (8*odd)

typedef __bf16 bf16x8 __attribute__((ext_vector_type(8)));
typedef __bf16 bf16x4 __attribute__((ext_vector_type(4)));
typedef float  f32x4  __attribute__((ext_vector_type(4)));

// async global->LDS, 16B per lane; LDS dest = wave-uniform base + lane*16
__device__ __forceinline__ void gload_lds16(const void* g, void* l) {
    __builtin_amdgcn_global_load_lds(
        (const __attribute__((address_space(1))) void*)g,
        (__attribute__((address_space(3))) void*)l, 16, 0, 0);
}

#define MEMF() asm volatile("" ::: "memory")
#define BARRIER() do { MEMF(); __builtin_amdgcn_s_barrier(); MEMF(); } while (0)
#define WAITV(n) asm volatile("s_waitcnt vmcnt(" #n ")" ::: "memory")

// ---------------- merged f32 -> bf16 convert (x, w1, w2 in one launch) ----------------
#define XQ_  4210688           // x quads
#define W1Q_ 786432            // w1 quads
#define W2Q_ 262144            // w2 quads
__global__ __launch_bounds__(256) void cvt_all(const float* __restrict__ x,
                                               const float* __restrict__ w1,
                                               const float* __restrict__ w2,
                                               __bf16* __restrict__ xb,
                                               __bf16* __restrict__ w1b,
                                               __bf16* __restrict__ w2b) {
    int i = blockIdx.x * 256 + threadIdx.x;
    const float* src; __bf16* dst; int j;
    if (i < XQ_) { src = x; dst = xb; j = i; }
    else if (i < XQ_ + W1Q_) { src = w1; dst = w1b; j = i - XQ_; }
    else if (i < XQ_ + W1Q_ + W2Q_) { src = w2; dst = w2b; j = i - XQ_ - W1Q_; }
    else return;
    float4 v = reinterpret_cast<const float4*>(src)[j];
    bf16x4 o;
    o[0] = (__bf16)v.x; o[1] = (__bf16)v.y; o[2] = (__bf16)v.z; o[3] = (__bf16)v.w;
    *reinterpret_cast<bf16x4*>(dst + (size_t)j * 4) = o;
}

// ---------------- 256x256 8-wave pipelined GEMM (bt), 4 phases/K-tile ----------------
// Burst-issue ledger (per K-tile t): q0 issues ALL 8 staging loads of tile t+1
// (order AF,WF,WB,AB). Steady-state outstanding at q0 entry = {WB(t),AB(t)} (4).
//   q0: ds_read AF,WF(t); issue L(t+1)(8) -> 12; WAITV(10) [WB(t) landed, 4-phase dist]
//   q1: ds_read WB(t);                          WAITV(8)  [AB(t) landed, 5-phase dist]
//   q2: ds_read AB(t);                          (no wait)
//   q3: (regs only);                            WAITV(4)  [AF,WF(t+1) landed, 3-phase dist]
// Every wait precedes a barrier that precedes the dependent ds_read (cross-wave safe).
// Grids are exact multiples: qkv 64x12=768 (3 rounds), out 64x4=256 (1 round);
// the 64-row M-tail is handled by gemm_tail.
template<int NT, int MODE>   // NT = col tiles (12 qkv -> q/k/v scatter, 4 out -> f32)
__global__ __launch_bounds__(512, 2) void gemm256(const __bf16* __restrict__ A,
                                                  const __bf16* __restrict__ W,
                                                  const float* __restrict__ bias,
                                                  __bf16* __restrict__ qo,
                                                  __bf16* __restrict__ ko,
                                                  __bf16* __restrict__ vo,
                                                  float* __restrict__ fo) {
    __shared__ __align__(16) char smem[131072];
    constexpr int NWG = 64 * NT;
    constexpr int qd = NWG >> 3;
    const int orig = blockIdx.x;
    const int xcd = orig & 7, loc = orig >> 3;
    const int wgid = xcd * qd + loc;                 // NWG % 8 == 0: clean bijection
    const int rowt = wgid / NT, colt = wgid - rowt * NT;
    const int row0 = rowt * 256, col0 = colt * 256;

    const int tid = threadIdx.x, lane = tid & 63, wv = tid >> 6;
    const int wm = wv >> 2, wn = wv & 3;
    const int fr = lane & 15, fq = lane >> 4, frs = lane & 7;

    // staging: per-thread source offsets (elements), source-swizzled (g ^= row&7)
    const int pr = tid >> 3;                       // 0..63 within a 64-row piece
    const int pg = ((tid & 7) ^ (pr & 7)) * 8;
    int srcA[4];                                   // pieces rows {0,128 | 64,192}
    {
        const int prow[4] = {0, 128, 64, 192};
#pragma unroll
        for (int p = 0; p < 4; ++p) {
            const int rg = row0 + prow[p] + pr;    // always < M_ (tail handled elsewhere)
            srcA[p] = rg * 1024 + pg;
        }
    }
    int srcW[2], ldsW[2];                          // B-front sub-pieces e=0,1; back = +32 rows
#pragma unroll
    for (int e = 0; e < 2; ++e) {
        const int wb = (wv >> 1) * 64 + e * 16 + (wv & 1) * 8;
        srcW[e] = (col0 + wb + (lane >> 3)) * 1024 + pg;
        ldsW[e] = wb * 128;
    }
    char* const At0 = smem;
    char* const At1 = smem + 32768;
    char* const Wt0 = smem + 65536;
    char* const Wt1 = smem + 98304;

#define STG_AF(dst, kk) do { gload_lds16(A + srcA[0] + (kk), (dst) + wv * 1024); \
                             gload_lds16(A + srcA[1] + (kk), (dst) + 16384 + wv * 1024); } while (0)
#define STG_AB(dst, kk) do { gload_lds16(A + srcA[2] + (kk), (dst) + 8192 + wv * 1024); \
                             gload_lds16(A + srcA[3] + (kk), (dst) + 24576 + wv * 1024); } while (0)
#define STG_WF(dst, kk) do { gload_lds16(W + srcW[0] + (kk), (dst) + ldsW[0]); \
                             gload_lds16(W + srcW[1] + (kk), (dst) + ldsW[1]); } while (0)
#define STG_WB(dst, kk) do { gload_lds16(W + srcW[0] + 32768 + (kk), (dst) + ldsW[0] + 4096); \
                             gload_lds16(W + srcW[1] + 32768 + (kk), (dst) + ldsW[1] + 4096); } while (0)
#define LD_A(buf, rqo) do { \
    _Pragma("unroll") for (int i = 0; i < 4; ++i) \
    _Pragma("unroll") for (int ks = 0; ks < 2; ++ks) \
        af[i][ks] = *(const bf16x8*)((buf) + (wm * 128 + (rqo) + i * 16 + fr) * 128 \
                                           + (((ks * 4 + fq) ^ frs) << 4)); \
} while (0)
#define LD_B(buf, co, bw) do { \
    _Pragma("unroll") for (int j = 0; j < 2; ++j) \
    _Pragma("unroll") for (int ks = 0; ks < 2; ++ks) \
        bw[j][ks] = *(const bf16x8*)((buf) + (wn * 64 + (co) + j * 16 + fr) * 128 \
                                           + (((ks * 4 + fq) ^ frs) << 4)); \
} while (0)
#define MFMA_Q(i0, j0, bw) do { \
    __builtin_amdgcn_s_setprio(1); \
    _Pragma("unroll") for (int i = 0; i < 4; ++i) \
    _Pragma("unroll") for (int j = 0; j < 2; ++j) \
    _Pragma("unroll") for (int ks = 0; ks < 2; ++ks) \
        acc[(i0) + i][(j0) + j] = __builtin_amdgcn_mfma_f32_16x16x32_bf16( \
            af[i][ks], bw[j][ks], acc[(i0) + i][(j0) + j], 0, 0, 0); \
    __builtin_amdgcn_s_setprio(0); \
} while (0)

    f32x4 acc[8][4] = {};
    bf16x8 af[4][2], bw0[2][2], bw1[2][2];

    // prologue: stage tile 0 (burst), wait for A/B-front; {WB,AB}(0) stay in flight
    STG_AF(At0, 0); STG_WF(Wt0, 0); STG_WB(Wt0, 0); STG_AB(At0, 0);
    WAITV(4);
    BARRIER();

#pragma unroll 2
    for (int t = 0; t < 16; ++t) {
        char* const Ac = (t & 1) ? At1 : At0;
        char* const Wc = (t & 1) ? Wt1 : Wt0;
        char* const An = (t & 1) ? At0 : At1;
        char* const Wn = (t & 1) ? Wt0 : Wt1;
        const int kk = (t < 15) ? (t + 1) * 64 : 960;   // t=15: dummy re-stage (dead buf)
        // q0: rows rq0, cols c01; burst-issue all of tile t+1
        LD_A(Ac, 0);
        LD_B(Wc, 0, bw0);
        STG_AF(An, kk);
        STG_WF(Wn, kk);
        STG_WB(Wn, kk);
        STG_AB(An, kk);
        WAITV(10);
        BARRIER();
        MFMA_Q(0, 0, bw0);
        BARRIER();
        // q1: rq0, c23
        LD_B(Wc, 32, bw1);
        WAITV(8);
        BARRIER();
        MFMA_Q(0, 2, bw1);
        BARRIER();
        // q2: rq1, c23
        LD_A(Ac, 64);
        BARRIER();
        MFMA_Q(4, 2, bw1);
        BARRIER();
        // q3: rq1, c01 (all regs)
        WAITV(4);
        BARRIER();
        MFMA_Q(4, 0, bw0);
        BARRIER();
    }
    WAITV(0);      // drain dummy stages before smem reuse / exit
    BARRIER();

    if constexpr (MODE == 0) {
        // epilogue: acc -> LDS (bias+scale, XOR-swizzled cols) -> coalesced q/k/v scatter
        const int which = colt >> 2;
        __bf16* const dst = which == 0 ? qo : (which == 1 ? ko : vo);
        const float scale = which == 0 ? 0.125f : 1.0f;
        float bj[4];
#pragma unroll
        for (int j = 0; j < 4; ++j) bj[j] = bias[col0 + wn * 64 + j * 16 + fr];
        __bf16* const Ct = (__bf16*)smem;
#pragma unroll
        for (int i = 0; i < 8; ++i) {
            const int rb = wm * 128 + (i >> 2) * 64 + (i & 3) * 16 + fq * 4;
#pragma unroll
            for (int r = 0; r < 4; ++r) {
                const int row = rb + r;
#pragma unroll
                for (int j = 0; j < 4; ++j) {
                    const int cu = wn * 64 + j * 16 + fr;
                    Ct[row * 256 + (((cu >> 3) ^ (row & 7)) * 8) + (cu & 7)] =
                        (__bf16)((acc[i][j][r] + bj[j]) * scale);
                }
            }
        }
        BARRIER();
#pragma unroll
        for (int p = 0; p < 16; ++p) {
            const int row = p * 16 + (tid >> 5);
            const int m = row0 + row;
            const int gl = tid & 31;
            bf16x8 v = *(const bf16x8*)(Ct + row * 256 + ((gl ^ (row & 7)) * 8));
            const int cG = col0 + gl * 8;
            const int h = (cG >> 6) & 15, hd = cG & 63;
            const int bb = m / 257, nn = m - bb * 257;
            *reinterpret_cast<bf16x8*>(dst + ((size_t)(bb * 16 + h) * 257 + nn) * 64 + hd) = v;
        }
    } else {
        // epilogue: direct f32 stores + bias
        float bj[4];
#pragma unroll
        for (int j = 0; j < 4; ++j) bj[j] = bias[col0 + wn * 64 + j * 16 + fr];
#pragma unroll
        for (int i = 0; i < 8; ++i) {
            const int rb = wm * 128 + (i >> 2) * 64 + (i & 3) * 16 + fq * 4;
#pragma unroll
            for (int r = 0; r < 4; ++r) {
                const int m = row0 + rb + r;
                float* const p = fo + (size_t)m * 1024 + col0 + wn * 64 + fr;
#pragma unroll
                for (int j = 0; j < 4; ++j) p[j * 16] = acc[i][j][r] + bj[j];
            }
        }
    }
#undef STG_AF
#undef STG_AB
#undef STG_WF
#undef STG_WB
#undef LD_A
#undef LD_B
#undef MFMA_Q
}

// ---------------- M-tail GEMM: rows 16384..16447 (b=63, n=193..256), 64x128 tiles ------
// MODE 0: qkv (grid 24, cols 0..3071 -> q/k/v scatter); MODE 1: out (grid 8, f32 + bias)
template<int MODE>
__global__ __launch_bounds__(256) void gemm_tail(const __bf16* __restrict__ A,
                                                 const __bf16* __restrict__ W,
                                                 const float* __restrict__ bias,
                                                 __bf16* __restrict__ qo,
                                                 __bf16* __restrict__ ko,
                                                 __bf16* __restrict__ vo,
                                                 float* __restrict__ fo) {
    __shared__ __align__(16) __bf16 As[64 * 64];     // swizzled (g ^= r&7)
    __shared__ __align__(16) __bf16 Ws[128 * 64];
    const int col0 = blockIdx.x * 128;
    const int tid = threadIdx.x, lane = tid & 63, wv = tid >> 6;
    const int fr = lane & 15, fq = lane >> 4, frs = lane & 7;

    f32x4 acc[4][2] = {};
    for (int k0 = 0; k0 < 1024; k0 += 64) {
        __syncthreads();   // protect LDS from previous iteration's readers
#pragma unroll
        for (int i = 0; i < 2; ++i) {
            const int c = tid + i * 256;
            const int r = c >> 3, g = (c & 7) ^ (r & 7);
            gload_lds16(A + (size_t)(16384 + r) * 1024 + g * 8 + k0,
                        (char*)As + i * 4096 + wv * 1024);
        }
#pragma unroll
        for (int i = 0; i < 4; ++i) {
            const int c = tid + i * 256;
            const int r = c >> 3, g = (c & 7) ^ (r & 7);
            gload_lds16(W + (size_t)(col0 + r) * 1024 + g * 8 + k0,
                        (char*)Ws + i * 4096 + wv * 1024);
        }
        __syncthreads();   // drains vmcnt for all waves
#pragma unroll
        for (int ks = 0; ks < 2; ++ks) {
            const int goff = ((ks * 4 + fq) ^ frs) * 8;
            bf16x8 af[4], bw[2];
#pragma unroll
            for (int i = 0; i < 4; ++i)
                af[i] = *reinterpret_cast<const bf16x8*>(&As[(i * 16 + fr) * 64 + goff]);
#pragma unroll
            for (int j = 0; j < 2; ++j)
                bw[j] = *reinterpret_cast<const bf16x8*>(&Ws[(wv * 32 + j * 16 + fr) * 64 + goff]);
#pragma unroll
            for (int i = 0; i < 4; ++i)
#pragma unroll
                for (int j = 0; j < 2; ++j)
                    acc[i][j] = __builtin_amdgcn_mfma_f32_16x16x32_bf16(af[i], bw[j], acc[i][j], 0, 0, 0);
        }
    }
#pragma unroll
    for (int i = 0; i < 4; ++i)
#pragma unroll
        for (int r = 0; r < 4; ++r) {
            const int rowC = i * 16 + fq * 4 + r;        // 0..63
            const int nn = 193 + rowC;                   // b=63
#pragma unroll
            for (int j = 0; j < 2; ++j) {
                const int cG = col0 + wv * 32 + j * 16 + fr;
                if constexpr (MODE == 0) {
                    const int which = cG >> 10;
                    __bf16* const dst = which == 0 ? qo : (which == 1 ? ko : vo);
                    const float scale = which == 0 ? 0.125f : 1.0f;
                    const int h = (cG >> 6) & 15, hd = cG & 63;
                    dst[((size_t)(63 * 16 + h) * 257 + nn) * 64 + hd] =
                        (__bf16)((acc[i][j][r] + bias[cG]) * scale);
                } else {
                    fo[(size_t)(16384 + rowC) * 1024 + cG] = acc[i][j][r] + bias[cG];
                }
            }
        }
}

// ---------------- fused masked attention (rows 0..255; 3 key chunks of 96) ----------------
__global__ __launch_bounds__(256) void attn_kernel(const __bf16* __restrict__ qw,
                                                   const __bf16* __restrict__ kw,
                                                   const __bf16* __restrict__ vw,
                                                   const int* __restrict__ mask,
                                                   __bf16* __restrict__ attn) {
    const int bh = blockIdx.x;
    const int bb = bh >> 4, hh = bh & 15;
    const int q0 = blockIdx.y * 64;      // 0..192, all 64 rows valid
    const int tid = threadIdx.x, lane = tid & 63, wv = tid >> 6;
    const int fr = lane & 15, fq = lane >> 4;
    const float NEG_INF = -__builtin_inff();

    __shared__ __align__(16) __bf16 Qs[64 * 64];        // [q][hd] swizzled (g ^= row&7)
    __shared__ __align__(16) __bf16 Ks[CK_ * 64];       // [key][hd] swizzled
    __shared__ __align__(16) __bf16 Vt[64 * VTS_];      // [hd][keygrp swizzled]
    __shared__ __align__(16) __bf16 Pl[4][16 * PLS_];   // per-wave P
    __shared__ float maskb[288];

    const __bf16* qg = qw + ((size_t)bh * 257 + q0) * 64;
    const __bf16* kg = kw + (size_t)bh * 257 * 64;
    const __bf16* vg = vw + (size_t)bh * 257 * 64;
    const int* mg = mask + bb * 257;

    for (int idx = tid; idx < 288; idx += 256)
        maskb[idx] = (idx < 257 && mg[idx] == 0) ? 0.0f : NEG_INF;

    // stage Q tile [64][64] async, source-swizzled (all rows valid)
#pragma unroll
    for (int i = 0; i < 2; ++i) {
        const int c = tid + i * 256;
        const int r = c >> 3, g = (c & 7) ^ (r & 7);
        gload_lds16(qg + (size_t)r * 64 + g * 8, (char*)Qs + i * 4096 + wv * 1024);
    }

    float m_run[4] = {NEG_INF, NEG_INF, NEG_INF, NEG_INF};
    float l_run[4] = {};
    f32x4 Oa[4] = {};

    for (int c3 = 0; c3 < 3; ++c3) {
        const int k0 = c3 * CK_;
        __syncthreads();
#pragma unroll
        for (int i = 0; i < 3; ++i) {
            const int c = tid + i * 256;
            const int r = c >> 3, g = (c & 7) ^ (r & 7);
            if (k0 + r < 257)
                gload_lds16(kg + (size_t)(k0 + r) * 64 + g * 8, (char*)Ks + i * 4096 + wv * 1024);
        }
#pragma unroll
        for (int it = 0; it < 3; ++it) {
            const int t = tid + it * 256;
            const int key = t >> 3, grp = t & 7;
            if (k0 + key < 257) {
                bf16x8 v8 = *reinterpret_cast<const bf16x8*>(vg + (size_t)(k0 + key) * 64 + grp * 8);
#pragma unroll
                for (int u = 0; u < 8; ++u) {
                    const int hd = grp * 8 + u;
                    Vt[hd * VTS_ + (((key >> 3) ^ (hd & 7)) * 8) + (key & 7)] = v8[u];
                }
            }
        }
        __syncthreads();

        // S = Q K^T (+ mask bias); q pre-scaled by 1/8
        f32x4 s[6];
        {
            bf16x8 aq[2];
#pragma unroll
            for (int ks = 0; ks < 2; ++ks)
                aq[ks] = *reinterpret_cast<const bf16x8*>(
                    &Qs[(wv * 16 + fr) * 64 + (((ks * 4 + fq) ^ (fr & 7)) * 8)]);
#pragma unroll
            for (int nt = 0; nt < 6; ++nt) {
                f32x4 sa = {};
#pragma unroll
                for (int ks = 0; ks < 2; ++ks) {
                    bf16x8 bk = *reinterpret_cast<const bf16x8*>(
                        &Ks[(nt * 16 + fr) * 64 + (((ks * 4 + fq) ^ (fr & 7)) * 8)]);
                    sa = __builtin_amdgcn_mfma_f32_16x16x32_bf16(aq[ks], bk, sa, 0, 0, 0);
                }
                const float mb = maskb[k0 + nt * 16 + fr];
#pragma unroll
                for (int r = 0; r < 4; ++r) sa[r] += mb;
                s[nt] = sa;
            }
        }
        float alpha[4];
#pragma unroll
        for (int r = 0; r < 4; ++r) {
            float v = s[0][r];
#pragma unroll
            for (int nt = 1; nt < 6; ++nt) v = fmaxf(v, s[nt][r]);
            v = fmaxf(v, __shfl_xor(v, 1));
            v = fmaxf(v, __shfl_xor(v, 2));
            v = fmaxf(v, __shfl_xor(v, 4));
            v = fmaxf(v, __shfl_xor(v, 8));
            const float mnew = fmaxf(m_run[r], v);
            alpha[r] = __expf(m_run[r] - mnew);
            m_run[r] = mnew;
        }
        float sm[4] = {};
#pragma unroll
        for (int nt = 0; nt < 6; ++nt)
#pragma unroll
            for (int r = 0; r < 4; ++r) {
                const float p = __expf(s[nt][r] - m_run[r]);
                s[nt][r] = p;
                sm[r] += p;
            }
#pragma unroll
        for (int r = 0; r < 4; ++r) {
            float v = sm[r];
            v += __shfl_xor(v, 1);
            v += __shfl_xor(v, 2);
            v += __shfl_xor(v, 4);
            v += __shfl_xor(v, 8);
            l_run[r] = l_run[r] * alpha[r] + v;
        }
#pragma unroll
        for (int ot = 0; ot < 4; ++ot)
#pragma unroll
            for (int r = 0; r < 4; ++r) Oa[ot][r] *= alpha[r];
#pragma unroll
        for (int nt = 0; nt < 6; ++nt)
#pragma unroll
            for (int r = 0; r < 4; ++r)
                Pl[wv][(fq * 4 + r) * PLS_ + nt * 16 + fr] = (__bf16)s[nt][r];
        __syncthreads();
        bf16x8 ap[3];
#pragma unroll
        for (int kk = 0; kk < 3; ++kk)
            ap[kk] = *reinterpret_cast<const bf16x8*>(&Pl[wv][fr * PLS_ + kk * 32 + fq * 8]);
#pragma unroll
        for (int ot = 0; ot < 4; ++ot) {
            const int row = ot * 16 + fr;
#pragma unroll
            for (int kk = 0; kk < 3; ++kk) {
                bf16x8 bv = *reinterpret_cast<const bf16x8*>(
                    &Vt[row * VTS_ + (((kk * 4 + fq) ^ (fr & 7)) * 8)]);
                Oa[ot] = __builtin_amdgcn_mfma_f32_16x16x32_bf16(ap[kk], bv, Oa[ot], 0, 0, 0);
            }
        }
    }
    // epilogue (all rows valid)
#pragma unroll
    for (int r = 0; r < 4; ++r) {
        const int n = q0 + wv * 16 + fq * 4 + r;
        const float inv = 1.0f / l_run[r];
#pragma unroll
        for (int ot = 0; ot < 4; ++ot)
            attn[((size_t)(bb * 257 + n)) * 1024 + hh * 64 + ot * 16 + fr] =
                (__bf16)(Oa[ot][r] * inv);
    }
}

// ---------------- attention tail: query row 256, one block per (b,h) ----------------
__global__ __launch_bounds__(320) void attn_tail(const __bf16* __restrict__ qw,
                                                 const __bf16* __restrict__ kw,
                                                 const __bf16* __restrict__ vw,
                                                 const int* __restrict__ mask,
                                                 __bf16* __restrict__ attn) {
    const int bh = blockIdx.x;
    const int bb = bh >> 4, hh = bh & 15;
    const int tid = threadIdx.x, wv = tid >> 6;
    const float NEG_INF = -__builtin_inff();
    __shared__ float pbuf[257];
    __shared__ float red[5];
    __shared__ float gstat[2];   // [0]=max, [1]=sum

    const __bf16* qg = qw + ((size_t)bh * 257 + 256) * 64;
    const __bf16* kg = kw + (size_t)bh * 257 * 64;
    const __bf16* vg = vw + (size_t)bh * 257 * 64;

    float s = NEG_INF;
    if (tid < 257) {
        const __bf16* kr = kg + (size_t)tid * 64;
        float acc = 0.0f;
#pragma unroll
        for (int g = 0; g < 8; ++g) {
            bf16x8 qv = *reinterpret_cast<const bf16x8*>(qg + g * 8);
            bf16x8 kv = *reinterpret_cast<const bf16x8*>(kr + g * 8);
#pragma unroll
            for (int u = 0; u < 8; ++u) acc += (float)qv[u] * (float)kv[u];
        }
        s = (mask[bb * 257 + tid] == 0) ? acc : NEG_INF;   // q pre-scaled by 1/8
    }
    // block max
    float v = s;
#pragma unroll
    for (int d = 1; d < 64; d <<= 1) v = fmaxf(v, __shfl_xor(v, d));
    if ((tid & 63) == 0) red[wv] = v;
    __syncthreads();
    if (tid == 0) {
        float m = red[0];
#pragma unroll
        for (int w = 1; w < 5; ++w) m = fmaxf(m, red[w]);
        gstat[0] = m;
    }
    __syncthreads();
    const float gmax = gstat[0];
    float p = (tid < 257) ? __expf(s - gmax) : 0.0f;
    if (tid < 257) pbuf[tid] = p;
    float sv = p;
#pragma unroll
    for (int d = 1; d < 64; d <<= 1) sv += __shfl_xor(sv, d);
    if ((tid & 63) == 0) red[wv] = sv;
    __syncthreads();
    if (tid == 0) gstat[1] = red[0] + red[1] + red[2] + red[3] + red[4];
    __syncthreads();
    if (tid < 64) {
        const float inv = 1.0f / gstat[1];
        float o = 0.0f;
        for (int j = 0; j < 257; ++j)
            o += pbuf[j] * (float)vg[(size_t)j * 64 + tid];
        attn[((size_t)(bb * 257 + 256)) * 1024 + hh * 64 + tid] = (__bf16)(o * inv);
    }
}

// ---------------- launch ----------------
// ws layout (bytes):
//   x_bf   @ 0          : 16512*1024*2    = 33,816,576
//   w1_bf  @ 33816576   : 3072*1024*2     =  6,291,456
//   w2_bf  @ 40108032   : 1024*1024*2     =  2,097,152
//   q_ws   @ 42205184   : 64*16*257*64*2  = 33,685,504   [b][h][n][hd], pre-scaled 1/8
//   k_ws   @ 75890688   : 33,685,504                      [b][h][n][hd]
//   v_ws   @ 109576192  : 33,685,504                      [b][h][n][hd]
//   a_bf   @ 143261696  : 33,816,576                      attention output, bf16
extern "C" void kernel_launch(void* const* d_in, const int* in_sizes, int n_in,
                              void* d_out, int out_size, void* d_ws, size_t ws_size,
                              hipStream_t stream) {
    const float* x  = (const float*)d_in[0];
    const int* mask = (const int*)d_in[1];
    const float* w1 = (const float*)d_in[2];
    const float* b1 = (const float*)d_in[3];
    const float* w2 = (const float*)d_in[4];
    const float* b2 = (const float*)d_in[5];
    float* out = (float*)d_out;
    char* ws = (char*)d_ws;
    __bf16* x_bf  = (__bf16*)(ws);
    __bf16* w1_bf = (__bf16*)(ws + 33816576);
    __bf16* w2_bf = (__bf16*)(ws + 40108032);
    __bf16* q_ws  = (__bf16*)(ws + 42205184);
    __bf16* k_ws  = (__bf16*)(ws + 75890688);
    __bf16* v_ws  = (__bf16*)(ws + 109576192);
    __bf16* a_bf  = (__bf16*)(ws + 143261696);

    cvt_all<<<20544, 256, 0, stream>>>(x, w1, w2, x_bf, w1_bf, w2_bf);
    gemm256<12, 0><<<768, 512, 0, stream>>>(x_bf, w1_bf, b1, q_ws, k_ws, v_ws, nullptr);
    gemm_tail<0><<<24, 256, 0, stream>>>(x_bf, w1_bf, b1, q_ws, k_ws, v_ws, nullptr);
    attn_kernel<<<dim3(1024, 4), 256, 0, stream>>>(q_ws, k_ws, v_ws, mask, a_bf);
    attn_tail<<<1024, 320, 0, stream>>>(q_ws, k_ws, v_ws, mask, a_bf);
    gemm256<4, 1><<<256, 512, 0, stream>>>(a_bf, w2_bf, b2, nullptr, nullptr, nullptr, out);
    gemm_tail<1><<<8, 256, 0, stream>>>(a_bf, w2_bf, b2, nullptr, nullptr, nullptr, out);
}

// Round 3
// 407.351 us; speedup vs baseline: 1.1169x; 1.0232x over previous
//
#include <hip/hip_runtime.h>

// Problem: B=64, N=257, D=1024, H=16, HD=64
#define B_   64
#define N_   257
#define D_   1024
#define H_   16
#define HD_  64
#define M_   (B_*N_)      // 16448 rows (b*257+n)
#define CK_  96           // attention key-chunk (3 chunks cover 288 >= 257)
#define VTS_ 128          // Vt row stride
#define PLS_ 104          // Pl row stride (8*odd)

typedef __bf16 bf16x8 __attribute__((ext_vector_type(8)));
typedef __bf16 bf16x4 __attribute__((ext_vector_type(4)));
typedef float  f32x4  __attribute__((ext_vector_type(4)));

// async global->LDS, 16B per lane; LDS dest = wave-uniform base + lane*16
__device__ __forceinline__ void gload_lds16(const void* g, void* l) {
    __builtin_amdgcn_global_load_lds(
        (const __attribute__((address_space(1))) void*)g,
        (__attribute__((address_space(3))) void*)l, 16, 0, 0);
}

#define MEMF() asm volatile("" ::: "memory")
#define BARRIER() do { MEMF(); __builtin_amdgcn_s_barrier(); MEMF(); } while (0)
#define WAITV(n) asm volatile("s_waitcnt vmcnt(" #n ")" ::: "memory")

// ---------------- merged f32 -> bf16 convert (x, w1, w2 in one launch) ----------------
#define XQ_  4210688           // x quads
#define W1Q_ 786432            // w1 quads
#define W2Q_ 262144            // w2 quads
__global__ __launch_bounds__(256) void cvt_all(const float* __restrict__ x,
                                               const float* __restrict__ w1,
                                               const float* __restrict__ w2,
                                               __bf16* __restrict__ xb,
                                               __bf16* __restrict__ w1b,
                                               __bf16* __restrict__ w2b) {
    int i = blockIdx.x * 256 + threadIdx.x;
    const float* src; __bf16* dst; int j;
    if (i < XQ_) { src = x; dst = xb; j = i; }
    else if (i < XQ_ + W1Q_) { src = w1; dst = w1b; j = i - XQ_; }
    else if (i < XQ_ + W1Q_ + W2Q_) { src = w2; dst = w2b; j = i - XQ_ - W1Q_; }
    else return;
    float4 v = reinterpret_cast<const float4*>(src)[j];
    bf16x4 o;
    o[0] = (__bf16)v.x; o[1] = (__bf16)v.y; o[2] = (__bf16)v.z; o[3] = (__bf16)v.w;
    *reinterpret_cast<bf16x4*>(dst + (size_t)j * 4) = o;
}

// ---------------- 256x256 8-wave GEMM (bt), barrier-minimal tile pipeline ----------------
// Per K-tile t: burst-issue ALL 8 staging loads of t+1 (other buffer) at tile start,
// then one barrier-free region: 24 ds_read + 64 MFMA (compiler schedules; 2 waves/SIMD
// desync via setprio -> MFMA overlaps the other wave's ds_read), then ONE
// WAITV(0)+BARRIER at tile end (loads issued a full tile ago -> drain ~free; barrier
// both publishes t+1 and separates next STG from this tile's reads).
// Grids exact: qkv 64x12=768 (3 rounds), out 64x4=256 (1 round); M-tail via gemm_tail.
template<int NT, int MODE>   // NT = col tiles (12 qkv -> q/k/v scatter, 4 out -> f32)
__global__ __launch_bounds__(512, 2) void gemm256(const __bf16* __restrict__ A,
                                                  const __bf16* __restrict__ W,
                                                  const float* __restrict__ bias,
                                                  __bf16* __restrict__ qo,
                                                  __bf16* __restrict__ ko,
                                                  __bf16* __restrict__ vo,
                                                  float* __restrict__ fo) {
    __shared__ __align__(16) char smem[131072];
    constexpr int NWG = 64 * NT;
    constexpr int qd = NWG >> 3;
    const int orig = blockIdx.x;
    const int xcd = orig & 7, loc = orig >> 3;
    const int wgid = xcd * qd + loc;                 // NWG % 8 == 0: clean bijection
    const int rowt = wgid / NT, colt = wgid - rowt * NT;
    const int row0 = rowt * 256, col0 = colt * 256;

    const int tid = threadIdx.x, lane = tid & 63, wv = tid >> 6;
    const int wm = wv >> 2, wn = wv & 3;
    const int fr = lane & 15, fq = lane >> 4, frs = lane & 7;

    // staging: per-thread source offsets (elements), source-swizzled (g ^= row&7)
    const int pr = tid >> 3;                       // 0..63 within a 64-row piece
    const int pg = ((tid & 7) ^ (pr & 7)) * 8;
    int srcA[4];                                   // pieces rows {0,128 | 64,192}
    {
        const int prow[4] = {0, 128, 64, 192};
#pragma unroll
        for (int p = 0; p < 4; ++p) {
            const int rg = row0 + prow[p] + pr;    // always < M_ (tail handled elsewhere)
            srcA[p] = rg * 1024 + pg;
        }
    }
    int srcW[2], ldsW[2];                          // B-front sub-pieces e=0,1; back = +32 rows
#pragma unroll
    for (int e = 0; e < 2; ++e) {
        const int wb = (wv >> 1) * 64 + e * 16 + (wv & 1) * 8;
        srcW[e] = (col0 + wb + (lane >> 3)) * 1024 + pg;
        ldsW[e] = wb * 128;
    }
    char* const At0 = smem;
    char* const At1 = smem + 32768;
    char* const Wt0 = smem + 65536;
    char* const Wt1 = smem + 98304;

#define STG_AF(dst, kk) do { gload_lds16(A + srcA[0] + (kk), (dst) + wv * 1024); \
                             gload_lds16(A + srcA[1] + (kk), (dst) + 16384 + wv * 1024); } while (0)
#define STG_AB(dst, kk) do { gload_lds16(A + srcA[2] + (kk), (dst) + 8192 + wv * 1024); \
                             gload_lds16(A + srcA[3] + (kk), (dst) + 24576 + wv * 1024); } while (0)
#define STG_WF(dst, kk) do { gload_lds16(W + srcW[0] + (kk), (dst) + ldsW[0]); \
                             gload_lds16(W + srcW[1] + (kk), (dst) + ldsW[1]); } while (0)
#define STG_WB(dst, kk) do { gload_lds16(W + srcW[0] + 32768 + (kk), (dst) + ldsW[0] + 4096); \
                             gload_lds16(W + srcW[1] + 32768 + (kk), (dst) + ldsW[1] + 4096); } while (0)
#define LD_A(buf, rqo) do { \
    _Pragma("unroll") for (int i = 0; i < 4; ++i) \
    _Pragma("unroll") for (int ks = 0; ks < 2; ++ks) \
        af[i][ks] = *(const bf16x8*)((buf) + (wm * 128 + (rqo) + i * 16 + fr) * 128 \
                                           + (((ks * 4 + fq) ^ frs) << 4)); \
} while (0)
#define LD_B(buf, co, bw) do { \
    _Pragma("unroll") for (int j = 0; j < 2; ++j) \
    _Pragma("unroll") for (int ks = 0; ks < 2; ++ks) \
        bw[j][ks] = *(const bf16x8*)((buf) + (wn * 64 + (co) + j * 16 + fr) * 128 \
                                           + (((ks * 4 + fq) ^ frs) << 4)); \
} while (0)
#define MFMA_Q(i0, j0, bw) do { \
    __builtin_amdgcn_s_setprio(1); \
    _Pragma("unroll") for (int i = 0; i < 4; ++i) \
    _Pragma("unroll") for (int j = 0; j < 2; ++j) \
    _Pragma("unroll") for (int ks = 0; ks < 2; ++ks) \
        acc[(i0) + i][(j0) + j] = __builtin_amdgcn_mfma_f32_16x16x32_bf16( \
            af[i][ks], bw[j][ks], acc[(i0) + i][(j0) + j], 0, 0, 0); \
    __builtin_amdgcn_s_setprio(0); \
} while (0)

    f32x4 acc[8][4] = {};
    bf16x8 af[4][2], bw0[2][2], bw1[2][2];

    // prologue: stage tile 0 fully
    STG_AF(At0, 0); STG_WF(Wt0, 0); STG_WB(Wt0, 0); STG_AB(At0, 0);
    WAITV(0);
    BARRIER();

#pragma unroll 2
    for (int t = 0; t < 16; ++t) {
        char* const Ac = (t & 1) ? At1 : At0;
        char* const Wc = (t & 1) ? Wt1 : Wt0;
        char* const An = (t & 1) ? At0 : At1;
        char* const Wn = (t & 1) ? Wt0 : Wt1;
        if (t < 15) {
            const int kk = (t + 1) * 64;
            STG_AF(An, kk); STG_WF(Wn, kk); STG_WB(Wn, kk); STG_AB(An, kk);
        }
        // barrier-free tile body: ds_read + MFMA, compiler/wave-desync overlap
        LD_A(Ac, 0);
        LD_B(Wc, 0, bw0);
        LD_B(Wc, 32, bw1);
        MFMA_Q(0, 0, bw0);
        MFMA_Q(0, 2, bw1);
        LD_A(Ac, 64);
        MFMA_Q(4, 2, bw1);
        MFMA_Q(4, 0, bw0);
        WAITV(0);      // loads were issued a full tile ago -> near-free drain
        BARRIER();     // publish t+1; separate next STG from this tile's reads
    }

    if constexpr (MODE == 0) {
        // epilogue: acc -> LDS (bias+scale, XOR-swizzled cols) -> coalesced q/k/v scatter
        const int which = colt >> 2;
        __bf16* const dst = which == 0 ? qo : (which == 1 ? ko : vo);
        const float scale = which == 0 ? 0.125f : 1.0f;
        float bj[4];
#pragma unroll
        for (int j = 0; j < 4; ++j) bj[j] = bias[col0 + wn * 64 + j * 16 + fr];
        __bf16* const Ct = (__bf16*)smem;
#pragma unroll
        for (int i = 0; i < 8; ++i) {
            const int rb = wm * 128 + (i >> 2) * 64 + (i & 3) * 16 + fq * 4;
#pragma unroll
            for (int r = 0; r < 4; ++r) {
                const int row = rb + r;
#pragma unroll
                for (int j = 0; j < 4; ++j) {
                    const int cu = wn * 64 + j * 16 + fr;
                    Ct[row * 256 + (((cu >> 3) ^ (row & 7)) * 8) + (cu & 7)] =
                        (__bf16)((acc[i][j][r] + bj[j]) * scale);
                }
            }
        }
        BARRIER();
#pragma unroll
        for (int p = 0; p < 16; ++p) {
            const int row = p * 16 + (tid >> 5);
            const int m = row0 + row;
            const int gl = tid & 31;
            bf16x8 v = *(const bf16x8*)(Ct + row * 256 + ((gl ^ (row & 7)) * 8));
            const int cG = col0 + gl * 8;
            const int h = (cG >> 6) & 15, hd = cG & 63;
            const int bb = m / 257, nn = m - bb * 257;
            *reinterpret_cast<bf16x8*>(dst + ((size_t)(bb * 16 + h) * 257 + nn) * 64 + hd) = v;
        }
    } else {
        // epilogue: direct f32 stores + bias
        float bj[4];
#pragma unroll
        for (int j = 0; j < 4; ++j) bj[j] = bias[col0 + wn * 64 + j * 16 + fr];
#pragma unroll
        for (int i = 0; i < 8; ++i) {
            const int rb = wm * 128 + (i >> 2) * 64 + (i & 3) * 16 + fq * 4;
#pragma unroll
            for (int r = 0; r < 4; ++r) {
                const int m = row0 + rb + r;
                float* const p = fo + (size_t)m * 1024 + col0 + wn * 64 + fr;
#pragma unroll
                for (int j = 0; j < 4; ++j) p[j * 16] = acc[i][j][r] + bj[j];
            }
        }
    }
#undef STG_AF
#undef STG_AB
#undef STG_WF
#undef STG_WB
#undef LD_A
#undef LD_B
#undef MFMA_Q
}

// ---------------- M-tail GEMM: rows 16384..16447 (b=63, n=193..256), 64x128 tiles ------
// MODE 0: qkv (grid 24, cols 0..3071 -> q/k/v scatter); MODE 1: out (grid 8, f32 + bias)
template<int MODE>
__global__ __launch_bounds__(256) void gemm_tail(const __bf16* __restrict__ A,
                                                 const __bf16* __restrict__ W,
                                                 const float* __restrict__ bias,
                                                 __bf16* __restrict__ qo,
                                                 __bf16* __restrict__ ko,
                                                 __bf16* __restrict__ vo,
                                                 float* __restrict__ fo) {
    __shared__ __align__(16) __bf16 As[64 * 64];     // swizzled (g ^= r&7)
    __shared__ __align__(16) __bf16 Ws[128 * 64];
    const int col0 = blockIdx.x * 128;
    const int tid = threadIdx.x, lane = tid & 63, wv = tid >> 6;
    const int fr = lane & 15, fq = lane >> 4, frs = lane & 7;

    f32x4 acc[4][2] = {};
    for (int k0 = 0; k0 < 1024; k0 += 64) {
        __syncthreads();   // protect LDS from previous iteration's readers
#pragma unroll
        for (int i = 0; i < 2; ++i) {
            const int c = tid + i * 256;
            const int r = c >> 3, g = (c & 7) ^ (r & 7);
            gload_lds16(A + (size_t)(16384 + r) * 1024 + g * 8 + k0,
                        (char*)As + i * 4096 + wv * 1024);
        }
#pragma unroll
        for (int i = 0; i < 4; ++i) {
            const int c = tid + i * 256;
            const int r = c >> 3, g = (c & 7) ^ (r & 7);
            gload_lds16(W + (size_t)(col0 + r) * 1024 + g * 8 + k0,
                        (char*)Ws + i * 4096 + wv * 1024);
        }
        __syncthreads();   // drains vmcnt for all waves
#pragma unroll
        for (int ks = 0; ks < 2; ++ks) {
            const int goff = ((ks * 4 + fq) ^ frs) * 8;
            bf16x8 af[4], bw[2];
#pragma unroll
            for (int i = 0; i < 4; ++i)
                af[i] = *reinterpret_cast<const bf16x8*>(&As[(i * 16 + fr) * 64 + goff]);
#pragma unroll
            for (int j = 0; j < 2; ++j)
                bw[j] = *reinterpret_cast<const bf16x8*>(&Ws[(wv * 32 + j * 16 + fr) * 64 + goff]);
#pragma unroll
            for (int i = 0; i < 4; ++i)
#pragma unroll
                for (int j = 0; j < 2; ++j)
                    acc[i][j] = __builtin_amdgcn_mfma_f32_16x16x32_bf16(af[i], bw[j], acc[i][j], 0, 0, 0);
        }
    }
#pragma unroll
    for (int i = 0; i < 4; ++i)
#pragma unroll
        for (int r = 0; r < 4; ++r) {
            const int rowC = i * 16 + fq * 4 + r;        // 0..63
            const int nn = 193 + rowC;                   // b=63
#pragma unroll
            for (int j = 0; j < 2; ++j) {
                const int cG = col0 + wv * 32 + j * 16 + fr;
                if constexpr (MODE == 0) {
                    const int which = cG >> 10;
                    __bf16* const dst = which == 0 ? qo : (which == 1 ? ko : vo);
                    const float scale = which == 0 ? 0.125f : 1.0f;
                    const int h = (cG >> 6) & 15, hd = cG & 63;
                    dst[((size_t)(63 * 16 + h) * 257 + nn) * 64 + hd] =
                        (__bf16)((acc[i][j][r] + bias[cG]) * scale);
                } else {
                    fo[(size_t)(16384 + rowC) * 1024 + cG] = acc[i][j][r] + bias[cG];
                }
            }
        }
}

// ---------------- fused masked attention (rows 0..255; 3 key chunks of 96) ----------------
__global__ __launch_bounds__(256) void attn_kernel(const __bf16* __restrict__ qw,
                                                   const __bf16* __restrict__ kw,
                                                   const __bf16* __restrict__ vw,
                                                   const int* __restrict__ mask,
                                                   __bf16* __restrict__ attn) {
    const int bh = blockIdx.x;
    const int bb = bh >> 4, hh = bh & 15;
    const int q0 = blockIdx.y * 64;      // 0..192, all 64 rows valid
    const int tid = threadIdx.x, lane = tid & 63, wv = tid >> 6;
    const int fr = lane & 15, fq = lane >> 4;
    const float NEG_INF = -__builtin_inff();

    __shared__ __align__(16) __bf16 Qs[64 * 64];        // [q][hd] swizzled (g ^= row&7)
    __shared__ __align__(16) __bf16 Ks[CK_ * 64];       // [key][hd] swizzled
    __shared__ __align__(16) __bf16 Vt[64 * VTS_];      // [hd][keygrp swizzled]
    __shared__ __align__(16) __bf16 Pl[4][16 * PLS_];   // per-wave P
    __shared__ float maskb[288];

    const __bf16* qg = qw + ((size_t)bh * 257 + q0) * 64;
    const __bf16* kg = kw + (size_t)bh * 257 * 64;
    const __bf16* vg = vw + (size_t)bh * 257 * 64;
    const int* mg = mask + bb * 257;

    for (int idx = tid; idx < 288; idx += 256)
        maskb[idx] = (idx < 257 && mg[idx] == 0) ? 0.0f : NEG_INF;

    // stage Q tile [64][64] async, source-swizzled (all rows valid)
#pragma unroll
    for (int i = 0; i < 2; ++i) {
        const int c = tid + i * 256;
        const int r = c >> 3, g = (c & 7) ^ (r & 7);
        gload_lds16(qg + (size_t)r * 64 + g * 8, (char*)Qs + i * 4096 + wv * 1024);
    }

    float m_run[4] = {NEG_INF, NEG_INF, NEG_INF, NEG_INF};
    float l_run[4] = {};
    f32x4 Oa[4] = {};

    for (int c3 = 0; c3 < 3; ++c3) {
        const int k0 = c3 * CK_;
        __syncthreads();
#pragma unroll
        for (int i = 0; i < 3; ++i) {
            const int c = tid + i * 256;
            const int r = c >> 3, g = (c & 7) ^ (r & 7);
            if (k0 + r < 257)
                gload_lds16(kg + (size_t)(k0 + r) * 64 + g * 8, (char*)Ks + i * 4096 + wv * 1024);
        }
#pragma unroll
        for (int it = 0; it < 3; ++it) {
            const int t = tid + it * 256;
            const int key = t >> 3, grp = t & 7;
            if (k0 + key < 257) {
                bf16x8 v8 = *reinterpret_cast<const bf16x8*>(vg + (size_t)(k0 + key) * 64 + grp * 8);
#pragma unroll
                for (int u = 0; u < 8; ++u) {
                    const int hd = grp * 8 + u;
                    Vt[hd * VTS_ + (((key >> 3) ^ (hd & 7)) * 8) + (key & 7)] = v8[u];
                }
            }
        }
        __syncthreads();

        // S = Q K^T (+ mask bias); q pre-scaled by 1/8
        f32x4 s[6];
        {
            bf16x8 aq[2];
#pragma unroll
            for (int ks = 0; ks < 2; ++ks)
                aq[ks] = *reinterpret_cast<const bf16x8*>(
                    &Qs[(wv * 16 + fr) * 64 + (((ks * 4 + fq) ^ (fr & 7)) * 8)]);
#pragma unroll
            for (int nt = 0; nt < 6; ++nt) {
                f32x4 sa = {};
#pragma unroll
                for (int ks = 0; ks < 2; ++ks) {
                    bf16x8 bk = *reinterpret_cast<const bf16x8*>(
                        &Ks[(nt * 16 + fr) * 64 + (((ks * 4 + fq) ^ (fr & 7)) * 8)]);
                    sa = __builtin_amdgcn_mfma_f32_16x16x32_bf16(aq[ks], bk, sa, 0, 0, 0);
                }
                const float mb = maskb[k0 + nt * 16 + fr];
#pragma unroll
                for (int r = 0; r < 4; ++r) sa[r] += mb;
                s[nt] = sa;
            }
        }
        float alpha[4];
#pragma unroll
        for (int r = 0; r < 4; ++r) {
            float v = s[0][r];
#pragma unroll
            for (int nt = 1; nt < 6; ++nt) v = fmaxf(v, s[nt][r]);
            v = fmaxf(v, __shfl_xor(v, 1));
            v = fmaxf(v, __shfl_xor(v, 2));
            v = fmaxf(v, __shfl_xor(v, 4));
            v = fmaxf(v, __shfl_xor(v, 8));
            const float mnew = fmaxf(m_run[r], v);
            alpha[r] = __expf(m_run[r] - mnew);
            m_run[r] = mnew;
        }
        float sm[4] = {};
#pragma unroll
        for (int nt = 0; nt < 6; ++nt)
#pragma unroll
            for (int r = 0; r < 4; ++r) {
                const float p = __expf(s[nt][r] - m_run[r]);
                s[nt][r] = p;
                sm[r] += p;
            }
#pragma unroll
        for (int r = 0; r < 4; ++r) {
            float v = sm[r];
            v += __shfl_xor(v, 1);
            v += __shfl_xor(v, 2);
            v += __shfl_xor(v, 4);
            v += __shfl_xor(v, 8);
            l_run[r] = l_run[r] * alpha[r] + v;
        }
#pragma unroll
        for (int ot = 0; ot < 4; ++ot)
#pragma unroll
            for (int r = 0; r < 4; ++r) Oa[ot][r] *= alpha[r];
#pragma unroll
        for (int nt = 0; nt < 6; ++nt)
#pragma unroll
            for (int r = 0; r < 4; ++r)
                Pl[wv][(fq * 4 + r) * PLS_ + nt * 16 + fr] = (__bf16)s[nt][r];
        __syncthreads();
        bf16x8 ap[3];
#pragma unroll
        for (int kk = 0; kk < 3; ++kk)
            ap[kk] = *reinterpret_cast<const bf16x8*>(&Pl[wv][fr * PLS_ + kk * 32 + fq * 8]);
#pragma unroll
        for (int ot = 0; ot < 4; ++ot) {
            const int row = ot * 16 + fr;
#pragma unroll
            for (int kk = 0; kk < 3; ++kk) {
                bf16x8 bv = *reinterpret_cast<const bf16x8*>(
                    &Vt[row * VTS_ + (((kk * 4 + fq) ^ (fr & 7)) * 8)]);
                Oa[ot] = __builtin_amdgcn_mfma_f32_16x16x32_bf16(ap[kk], bv, Oa[ot], 0, 0, 0);
            }
        }
    }
    // epilogue (all rows valid)
#pragma unroll
    for (int r = 0; r < 4; ++r) {
        const int n = q0 + wv * 16 + fq * 4 + r;
        const float inv = 1.0f / l_run[r];
#pragma unroll
        for (int ot = 0; ot < 4; ++ot)
            attn[((size_t)(bb * 257 + n)) * 1024 + hh * 64 + ot * 16 + fr] =
                (__bf16)(Oa[ot][r] * inv);
    }
}

// ---------------- attention tail: query row 256, one block per (b,h) ----------------
__global__ __launch_bounds__(320) void attn_tail(const __bf16* __restrict__ qw,
                                                 const __bf16* __restrict__ kw,
                                                 const __bf16* __restrict__ vw,
                                                 const int* __restrict__ mask,
                                                 __bf16* __restrict__ attn) {
    const int bh = blockIdx.x;
    const int bb = bh >> 4, hh = bh & 15;
    const int tid = threadIdx.x, wv = tid >> 6;
    const float NEG_INF = -__builtin_inff();
    __shared__ float pbuf[257];
    __shared__ float red[5];
    __shared__ float gstat[2];   // [0]=max, [1]=sum

    const __bf16* qg = qw + ((size_t)bh * 257 + 256) * 64;
    const __bf16* kg = kw + (size_t)bh * 257 * 64;
    const __bf16* vg = vw + (size_t)bh * 257 * 64;

    float s = NEG_INF;
    if (tid < 257) {
        const __bf16* kr = kg + (size_t)tid * 64;
        float acc = 0.0f;
#pragma unroll
        for (int g = 0; g < 8; ++g) {
            bf16x8 qv = *reinterpret_cast<const bf16x8*>(qg + g * 8);
            bf16x8 kv = *reinterpret_cast<const bf16x8*>(kr + g * 8);
#pragma unroll
            for (int u = 0; u < 8; ++u) acc += (float)qv[u] * (float)kv[u];
        }
        s = (mask[bb * 257 + tid] == 0) ? acc : NEG_INF;   // q pre-scaled by 1/8
    }
    // block max
    float v = s;
#pragma unroll
    for (int d = 1; d < 64; d <<= 1) v = fmaxf(v, __shfl_xor(v, d));
    if ((tid & 63) == 0) red[wv] = v;
    __syncthreads();
    if (tid == 0) {
        float m = red[0];
#pragma unroll
        for (int w = 1; w < 5; ++w) m = fmaxf(m, red[w]);
        gstat[0] = m;
    }
    __syncthreads();
    const float gmax = gstat[0];
    float p = (tid < 257) ? __expf(s - gmax) : 0.0f;
    if (tid < 257) pbuf[tid] = p;
    float sv = p;
#pragma unroll
    for (int d = 1; d < 64; d <<= 1) sv += __shfl_xor(sv, d);
    if ((tid & 63) == 0) red[wv] = sv;
    __syncthreads();
    if (tid == 0) gstat[1] = red[0] + red[1] + red[2] + red[3] + red[4];
    __syncthreads();
    if (tid < 64) {
        const float inv = 1.0f / gstat[1];
        float o = 0.0f;
        for (int j = 0; j < 257; ++j)
            o += pbuf[j] * (float)vg[(size_t)j * 64 + tid];
        attn[((size_t)(bb * 257 + 256)) * 1024 + hh * 64 + tid] = (__bf16)(o * inv);
    }
}

// ---------------- launch ----------------
// ws layout (bytes):
//   x_bf   @ 0          : 16512*1024*2    = 33,816,576
//   w1_bf  @ 33816576   : 3072*1024*2     =  6,291,456
//   w2_bf  @ 40108032   : 1024*1024*2     =  2,097,152
//   q_ws   @ 42205184   : 64*16*257*64*2  = 33,685,504   [b][h][n][hd], pre-scaled 1/8
//   k_ws   @ 75890688   : 33,685,504                      [b][h][n][hd]
//   v_ws   @ 109576192  : 33,685,504                      [b][h][n][hd]
//   a_bf   @ 143261696  : 33,816,576                      attention output, bf16
extern "C" void kernel_launch(void* const* d_in, const int* in_sizes, int n_in,
                              void* d_out, int out_size, void* d_ws, size_t ws_size,
                              hipStream_t stream) {
    const float* x  = (const float*)d_in[0];
    const int* mask = (const int*)d_in[1];
    const float* w1 = (const float*)d_in[2];
    const float* b1 = (const float*)d_in[3];
    const float* w2 = (const float*)d_in[4];
    const float* b2 = (const float*)d_in[5];
    float* out = (float*)d_out;
    char* ws = (char*)d_ws;
    __bf16* x_bf  = (__bf16*)(ws);
    __bf16* w1_bf = (__bf16*)(ws + 33816576);
    __bf16* w2_bf = (__bf16*)(ws + 40108032);
    __bf16* q_ws  = (__bf16*)(ws + 42205184);
    __bf16* k_ws  = (__bf16*)(ws + 75890688);
    __bf16* v_ws  = (__bf16*)(ws + 109576192);
    __bf16* a_bf  = (__bf16*)(ws + 143261696);

    cvt_all<<<20544, 256, 0, stream>>>(x, w1, w2, x_bf, w1_bf, w2_bf);
    gemm256<12, 0><<<768, 512, 0, stream>>>(x_bf, w1_bf, b1, q_ws, k_ws, v_ws, nullptr);
    gemm_tail<0><<<24, 256, 0, stream>>>(x_bf, w1_bf, b1, q_ws, k_ws, v_ws, nullptr);
    attn_kernel<<<dim3(1024, 4), 256, 0, stream>>>(q_ws, k_ws, v_ws, mask, a_bf);
    attn_tail<<<1024, 320, 0, stream>>>(q_ws, k_ws, v_ws, mask, a_bf);
    gemm256<4, 1><<<256, 512, 0, stream>>>(a_bf, w2_bf, b2, nullptr, nullptr, nullptr, out);
    gemm_tail<1><<<8, 256, 0, stream>>>(a_bf, w2_bf, b2, nullptr, nullptr, nullptr, out);
}